// Round 7
// baseline (751.956 us; speedup 1.0000x reference)
//
#include <hip/hip_runtime.h>
#include <hip/hip_bf16.h>

// MoE layer, routed top-2 implementation.
// N=4096 tokens, D=768, F=3072, E=8. All inputs fp32; compute in f16 MFMA
// (fp32 accumulate), gating in fp64 for exact top-2 selection.

#define N_TOK 4096
#define DIM   768
#define FDIM  3072
#define NEXP  8

typedef __attribute__((ext_vector_type(8))) _Float16 f16x8;
typedef __attribute__((ext_vector_type(4))) _Float16 f16x4;
typedef __attribute__((ext_vector_type(4))) float     f32x4;

__device__ __forceinline__ float gelu_exact(float v) {
    return 0.5f * v * (1.0f + erff(v * 0.7071067811865475f));
}

// ---------------- cast x (fp32 -> f16), vectorized ----------------
__global__ __launch_bounds__(256) void cast_x_kernel(const float* __restrict__ x,
                                                     _Float16* __restrict__ xh) {
    int i = blockIdx.x * 256 + threadIdx.x;   // one float4 per thread, grid sized exactly
    float4 v = ((const float4*)x)[i];
    f16x4 o;
    o[0] = (_Float16)v.x; o[1] = (_Float16)v.y;
    o[2] = (_Float16)v.z; o[3] = (_Float16)v.w;
    ((f16x4*)xh)[i] = o;
}

// ---------------- merged transpose + cast for w1 and w2 ----------------
// fp32 [E][R][C] -> f16 [E][C][R]; blockIdx.y: 0..7 = w1 experts, 8..15 = w2.
__global__ __launch_bounds__(256) void transpose_cast2_kernel(const float* __restrict__ w1,
                                                              const float* __restrict__ w2,
                                                              _Float16* __restrict__ w1t,
                                                              _Float16* __restrict__ w2t) {
    const int z     = blockIdx.y;
    const int which = z >> 3;
    const int e     = z & 7;
    const float* in; _Float16* out; int R, C, tx, ty;
    if (which == 0) { in = w1; out = w1t; R = DIM;  C = FDIM; tx = blockIdx.x % (FDIM / 64); ty = blockIdx.x / (FDIM / 64); }
    else            { in = w2; out = w2t; R = FDIM; C = DIM;  tx = blockIdx.x % (DIM  / 64); ty = blockIdx.x / (DIM  / 64); }
    const size_t eoff = (size_t)e * R * C;
    const int c0 = tx * 64;
    const int r0 = ty * 64;
    __shared__ _Float16 tile[64][66];   // pitch 66 to soften bank conflicts
    const int t = threadIdx.x;
    #pragma unroll
    for (int it = 0; it < 4; it++) {
        int lin = it * 256 + t;
        int r  = lin >> 4;       // 0..63
        int c4 = lin & 15;       // float4 column group
        float4 v = *(const float4*)&in[eoff + (size_t)(r0 + r) * C + c0 + c4 * 4];
        tile[r][c4 * 4 + 0] = (_Float16)v.x;
        tile[r][c4 * 4 + 1] = (_Float16)v.y;
        tile[r][c4 * 4 + 2] = (_Float16)v.z;
        tile[r][c4 * 4 + 3] = (_Float16)v.w;
    }
    __syncthreads();
    #pragma unroll
    for (int it = 0; it < 4; it++) {
        int lin = it * 256 + t;
        int c  = lin >> 4;       // out row (= original column)
        int r4 = lin & 15;       // group of 4 original rows
        f16x4 o;
        #pragma unroll
        for (int j = 0; j < 4; j++) o[j] = tile[r4 * 4 + j][c];
        *(f16x4*)&out[eoff + (size_t)(c0 + c) * R + r0 + r4 * 4] = o;
    }
}

// ---------------- gating: fp64 logits, softmax, top-2, per-expert lists ----------------
__global__ __launch_bounds__(256) void gate_kernel(const float* __restrict__ x,
                                                   const float* __restrict__ gw,
                                                   const float* __restrict__ gb,
                                                   int* __restrict__ tok_list,
                                                   float* __restrict__ wt_list,
                                                   int* __restrict__ count) {
    const int gtid = blockIdx.x * 256 + threadIdx.x;
    const int n    = gtid >> 6;        // one wave per token
    const int lane = threadIdx.x & 63;
    if (n >= N_TOK) return;
    double part[NEXP];
    #pragma unroll
    for (int e = 0; e < NEXP; e++) part[e] = 0.0;
    for (int d = lane; d < DIM; d += 64) {
        float xv = x[n * DIM + d];
        const float* g = &gw[d * NEXP];
        #pragma unroll
        for (int e = 0; e < NEXP; e++) part[e] += (double)xv * (double)g[e];
    }
    #pragma unroll
    for (int e = 0; e < NEXP; e++) {
        double v = part[e];
        #pragma unroll
        for (int off = 32; off > 0; off >>= 1) v += __shfl_xor(v, off);
        part[e] = v + (double)gb[e];
    }
    if (lane == 0) {
        double mx = part[0];
        #pragma unroll
        for (int e = 1; e < NEXP; e++) mx = fmax(mx, part[e]);
        double ex[NEXP]; double s = 0.0;
        #pragma unroll
        for (int e = 0; e < NEXP; e++) { ex[e] = exp(part[e] - mx); s += ex[e]; }
        int i0 = 0;
        #pragma unroll
        for (int e = 1; e < NEXP; e++) if (ex[e] > ex[i0]) i0 = e;   // first-max tie-break, matches top_k
        int i1 = (i0 == 0) ? 1 : 0;
        #pragma unroll
        for (int e = 0; e < NEXP; e++) if (e != i0 && ex[e] > ex[i1]) i1 = e;
        float g0 = (float)(ex[i0] / s), g1 = (float)(ex[i1] / s);
        float dn = g0 + g1 + 1e-9f;
        float w0 = g0 / dn, w1 = g1 / dn;
        int s0 = atomicAdd(&count[i0], 1);
        tok_list[i0 * N_TOK + s0] = n;  wt_list[i0 * N_TOK + s0] = w0;
        int s1 = atomicAdd(&count[i1], 1);
        tok_list[i1 * N_TOK + s1] = n;  wt_list[i1 * N_TOK + s1] = w1;
    }
}

// ---------------- tiny prefix scan over 8 expert counts ----------------
__global__ void scan_kernel(const int* __restrict__ count, int* __restrict__ basep) {
    if (threadIdx.x == 0) {
        int s = 0;
        for (int e = 0; e < NEXP; e++) { basep[e] = s; s += count[e]; }
    }
}

// ---------------- GEMM1: h = gelu(x_gathered @ w1[e] + b1[e]) ----------------
// DIRECT-REGISTER GEMM: no LDS, no barriers. All MFMA fragments are loaded
// straight from global to VGPRs as 16-B f16x8 loads (AITER-flatmm style).
// Rationale: xh is 6.3 MB (L2-resident), per-expert w1t panel is 4.7 MB
// (~one XCD L2) -- LDS staging of cache-resident data was pure overhead
// (110k of 252k cy/CU was LDS traffic + un-hideable vmcnt(0) drains).
// The barrier-free k-loop lets the compiler software-pipeline loads with
// counted vmcnt, and 5-6 blocks/CU of TLP covers L2 latency.
// 128x128 tile, 2x2 waves, 4x4 16x16x32 fragments per wave.
// MFMA operands SWAPPED (mfma(bf,af)) -> D: token=lane&15, 4 consecutive h
// columns per reg quad -> vectorized f16x4 epilogue stores (verified r6).
__global__ __launch_bounds__(256) void mm1_kernel(const _Float16* __restrict__ xh,
                                                  const _Float16* __restrict__ w1t,
                                                  const float* __restrict__ bias1,
                                                  const int* __restrict__ tok_list,
                                                  const int* __restrict__ count,
                                                  const int* __restrict__ basep,
                                                  _Float16* __restrict__ h) {
    const int e    = blockIdx.y;
    const int cnt  = count[e];
    const int row0 = blockIdx.z * 128;
    if (row0 >= cnt) return;
    const int col0 = blockIdx.x * 128;
    const int t    = threadIdx.x;
    const int lane = t & 63;
    const int wv   = t >> 6;
    const int wy   = wv >> 1, wx = wv & 1;
    const int m_lane = lane & 15, quad = lane >> 4;

    // per-lane fragment base pointers (k-offset quad*8 folded in)
    const _Float16* pA[4];
    #pragma unroll
    for (int i = 0; i < 4; i++) {
        int r = row0 + wy * 64 + i * 16 + m_lane; if (r > cnt - 1) r = cnt - 1;
        pA[i] = xh + (size_t)tok_list[e * N_TOK + r] * DIM + quad * 8;
    }
    const _Float16* pB[4];
    #pragma unroll
    for (int j = 0; j < 4; j++)
        pB[j] = w1t + (size_t)e * FDIM * DIM
                    + (size_t)(col0 + wx * 64 + j * 16 + m_lane) * DIM + quad * 8;

    f32x4 acc[4][4];
    #pragma unroll
    for (int i = 0; i < 4; i++)
        #pragma unroll
        for (int j = 0; j < 4; j++)
            acc[i][j] = (f32x4){0.f, 0.f, 0.f, 0.f};

    #pragma unroll 4
    for (int kk = 0; kk < DIM; kk += 32) {
        f16x8 af[4], bf[4];
        #pragma unroll
        for (int i = 0; i < 4; i++) af[i] = *(const f16x8*)(pA[i] + kk);
        #pragma unroll
        for (int j = 0; j < 4; j++) bf[j] = *(const f16x8*)(pB[j] + kk);
        #pragma unroll
        for (int i = 0; i < 4; i++)
            #pragma unroll
            for (int j = 0; j < 4; j++)
                acc[i][j] = __builtin_amdgcn_mfma_f32_16x16x32_f16(bf[j], af[i], acc[i][j], 0, 0, 0);
    }

    // epilogue (swapped layout, verified r6): value(lane, reg r) =
    //   h[token = row0+wy*64+i*16+m_lane][col = col0+wx*64+j*16+quad*4+r]
    const int hbase = basep[e];
    #pragma unroll
    for (int i = 0; i < 4; i++) {
        int gr = row0 + wy * 64 + i * 16 + m_lane;      // token row
        if (gr < cnt) {
            _Float16* hrow = h + (size_t)(hbase + gr) * FDIM;
            #pragma unroll
            for (int j = 0; j < 4; j++) {
                int c = col0 + wx * 64 + j * 16 + quad * 4;
                float4 b4 = *(const float4*)&bias1[e * FDIM + c];
                f16x4 o;
                o[0] = (_Float16)gelu_exact(acc[i][j][0] + b4.x);
                o[1] = (_Float16)gelu_exact(acc[i][j][1] + b4.y);
                o[2] = (_Float16)gelu_exact(acc[i][j][2] + b4.z);
                o[3] = (_Float16)gelu_exact(acc[i][j][3] + b4.w);
                *(f16x4*)&hrow[c] = o;
            }
        }
    }
}

// ---------------- GEMM2: out += gate_w * (h @ w2[e] + b2[e]) ----------------
// DIRECT-REGISTER GEMM like mm1. 64x128 tile (768 live blocks, 3/CU), 2x2
// waves (each 32 rows x 64 cols -> A-redundancy only x2; hbuf is L3-resident,
// w2t panel ~L2-resident). NON-swapped operand order + r5-verified epilogue:
// per wave-op atomics cover 4 rows x 16 consecutive cols (keeps WRITE ~25 MB;
// r6's scattered variant quadrupled it).
__global__ __launch_bounds__(256) void mm2_kernel(const _Float16* __restrict__ h,
                                                  const _Float16* __restrict__ w2t,
                                                  const float* __restrict__ bias2,
                                                  const int* __restrict__ tok_list,
                                                  const float* __restrict__ wt_list,
                                                  const int* __restrict__ count,
                                                  const int* __restrict__ basep,
                                                  float* __restrict__ out) {
    const int e    = blockIdx.y;
    const int cnt  = count[e];
    const int row0 = blockIdx.z * 64;
    if (row0 >= cnt) return;
    const int col0 = blockIdx.x * 128;
    const int t    = threadIdx.x;
    const int lane = t & 63;
    const int wv   = t >> 6;
    const int wy   = wv >> 1, wx = wv & 1;   // wave tile: 32 rows x 64 cols
    const int m_lane = lane & 15, quad = lane >> 4;

    const int hbase = basep[e];
    const _Float16* pA[2];
    #pragma unroll
    for (int i = 0; i < 2; i++) {
        int r = row0 + wy * 32 + i * 16 + m_lane; if (r > cnt - 1) r = cnt - 1;
        pA[i] = h + (size_t)(hbase + r) * FDIM + quad * 8;
    }
    const _Float16* pB[4];
    #pragma unroll
    for (int j = 0; j < 4; j++)
        pB[j] = w2t + (size_t)e * DIM * FDIM
                    + (size_t)(col0 + wx * 64 + j * 16 + m_lane) * FDIM + quad * 8;

    f32x4 acc[2][4];
    #pragma unroll
    for (int i = 0; i < 2; i++)
        #pragma unroll
        for (int j = 0; j < 4; j++)
            acc[i][j] = (f32x4){0.f, 0.f, 0.f, 0.f};

    #pragma unroll 4
    for (int kk = 0; kk < FDIM; kk += 32) {
        f16x8 af[2], bf[4];
        #pragma unroll
        for (int i = 0; i < 2; i++) af[i] = *(const f16x8*)(pA[i] + kk);
        #pragma unroll
        for (int j = 0; j < 4; j++) bf[j] = *(const f16x8*)(pB[j] + kk);
        #pragma unroll
        for (int i = 0; i < 2; i++)
            #pragma unroll
            for (int j = 0; j < 4; j++)
                acc[i][j] = __builtin_amdgcn_mfma_f32_16x16x32_f16(af[i], bf[j], acc[i][j], 0, 0, 0);
    }

    // epilogue (non-swapped, r5-verified): value(lane, reg r) =
    //   out[token = row0+wy*32+i*16+quad*4+r][col = col0+wx*64+j*16+m_lane]
    #pragma unroll
    for (int i = 0; i < 2; i++) {
        #pragma unroll
        for (int r = 0; r < 4; r++) {
            int gr = row0 + wy * 32 + i * 16 + quad * 4 + r;
            if (gr < cnt) {
                int tok   = tok_list[e * N_TOK + gr];
                float wgt = wt_list[e * N_TOK + gr];
                float* orow = out + (size_t)tok * DIM;
                #pragma unroll
                for (int j = 0; j < 4; j++) {
                    int c = col0 + wx * 64 + j * 16 + m_lane;
                    float v = acc[i][j][r] + bias2[e * DIM + c];
                    atomicAdd(&orow[c], wgt * v);
                }
            }
        }
    }
}

extern "C" void kernel_launch(void* const* d_in, const int* in_sizes, int n_in,
                              void* d_out, int out_size, void* d_ws, size_t ws_size,
                              hipStream_t stream) {
    const float* x  = (const float*)d_in[0];
    const float* gw = (const float*)d_in[1];
    const float* gb = (const float*)d_in[2];
    const float* w1 = (const float*)d_in[3];
    const float* b1 = (const float*)d_in[4];
    const float* w2 = (const float*)d_in[5];
    const float* b2 = (const float*)d_in[6];
    float* out = (float*)d_out;

    // workspace layout (all 16B-aligned); total ~132.4 MB
    char* ws = (char*)d_ws;
    _Float16* xh   = (_Float16*)ws;                                    // 4096*768
    _Float16* w1t  = xh  + (size_t)N_TOK * DIM;                        // [E][F][D]
    _Float16* w2t  = w1t + (size_t)NEXP * FDIM * DIM;                  // [E][D][F]
    _Float16* hbuf = w2t + (size_t)NEXP * DIM * FDIM;                  // [2N][F] compact slots
    int*   tok_list = (int*)(hbuf + (size_t)2 * N_TOK * FDIM);         // [E][N]
    float* wt_list  = (float*)(tok_list + NEXP * N_TOK);               // [E][N]
    int*   count    = (int*)(wt_list + NEXP * N_TOK);                  // [E]
    int*   basep    = count + 8;                                       // [E]

    hipMemsetAsync(count, 0, 64, stream);                 // count + base
    hipMemsetAsync(out, 0, (size_t)out_size * sizeof(float), stream);

    cast_x_kernel<<<dim3(N_TOK * DIM / 4 / 256), 256, 0, stream>>>(x, xh);
    // w1: [E][768][3072] -> w1t [E][3072][768]; w2: [E][3072][768] -> w2t [E][768][3072]
    transpose_cast2_kernel<<<dim3(576, 16), 256, 0, stream>>>(w1, w2, w1t, w2t);
    gate_kernel<<<dim3(N_TOK / 4), 256, 0, stream>>>(x, gw, gb, tok_list, wt_list, count);
    scan_kernel<<<1, 64, 0, stream>>>(count, basep);
    // grid: (cols, experts, rowblocks) -> live blocks are a dense prefix
    mm1_kernel<<<dim3(FDIM / 128, NEXP, N_TOK / 128), 256, 0, stream>>>(
        xh, w1t, b1, tok_list, count, basep, hbuf);
    mm2_kernel<<<dim3(DIM / 128, NEXP, N_TOK / 64), 256, 0, stream>>>(
        hbuf, w2t, b2, tok_list, wt_list, count, basep, out);
}

// Round 8
// 456.722 us; speedup vs baseline: 1.6464x; 1.6464x over previous
//
#include <hip/hip_runtime.h>
#include <hip/hip_bf16.h>

// MoE layer, routed top-2 implementation.
// N=4096 tokens, D=768, F=3072, E=8. All inputs fp32; compute in f16 MFMA
// (fp32 accumulate), gating in fp64 for exact top-2 selection.
// Round 8: GEMMs = round-5 verified structure (BK=64 + both-sides XOR swizzle,
// 0 bank conflicts); mm1 epilogue swapped-operand (vectorized f16x4 stores);
// launch count cut 8->5 (fused pre_kernel, scan folded into GEMMs).

#define N_TOK 4096
#define DIM   768
#define FDIM  3072
#define NEXP  8

#define TRANS_BLOCKS 9216   // 576 tiles x 16 (w1:8 experts + w2:8 experts)
#define GATE_BLOCKS  1024   // 4096 tokens / 4 waves
#define CAST_BLOCKS  3072   // 4096*768 / 4 / 256
#define PRE_BLOCKS   (TRANS_BLOCKS + GATE_BLOCKS + CAST_BLOCKS)

typedef __attribute__((ext_vector_type(8))) _Float16 f16x8;
typedef __attribute__((ext_vector_type(4))) _Float16 f16x4;
typedef __attribute__((ext_vector_type(4))) float     f32x4;

__device__ __forceinline__ float gelu_exact(float v) {
    return 0.5f * v * (1.0f + erff(v * 0.7071067811865475f));
}

// async global->LDS, 16B per lane. Dest must be wave-uniform base + lane*16.
__device__ __forceinline__ void gload_lds16(const _Float16* g, _Float16* l) {
    __builtin_amdgcn_global_load_lds(
        (const __attribute__((address_space(1))) void*)g,
        (__attribute__((address_space(3))) void*)l,
        16, 0, 0);
}

// ---------------- fused pre-pass: transpose+cast (w1,w2), gate, cast x ----------------
// Independent input-only ops merged into ONE launch; whole blocks take one
// branch, so no divergence cost. Saves 2 kernel dispatches (~launch gaps).
__global__ __launch_bounds__(256) void pre_kernel(const float* __restrict__ x,
                                                  const float* __restrict__ gw,
                                                  const float* __restrict__ gb,
                                                  const float* __restrict__ w1,
                                                  const float* __restrict__ w2,
                                                  _Float16* __restrict__ xh,
                                                  _Float16* __restrict__ w1t,
                                                  _Float16* __restrict__ w2t,
                                                  int* __restrict__ tok_list,
                                                  float* __restrict__ wt_list,
                                                  int* __restrict__ count) {
    const int bid = blockIdx.x;
    const int t   = threadIdx.x;

    if (bid < TRANS_BLOCKS) {
        // ---- transpose + cast: fp32 [E][R][C] -> f16 [E][C][R] ----
        const int z     = bid & 15;          // 0..7 = w1 experts, 8..15 = w2
        const int xx    = bid >> 4;          // 0..575 tile id
        const int which = z >> 3;
        const int e     = z & 7;
        const float* in; _Float16* out; int R, C, tx, ty;
        if (which == 0) { in = w1; out = w1t; R = DIM;  C = FDIM; tx = xx % (FDIM / 64); ty = xx / (FDIM / 64); }
        else            { in = w2; out = w2t; R = FDIM; C = DIM;  tx = xx % (DIM  / 64); ty = xx / (DIM  / 64); }
        const size_t eoff = (size_t)e * R * C;
        const int c0 = tx * 64;
        const int r0 = ty * 64;
        __shared__ _Float16 tile[64][66];   // pitch 66 to soften bank conflicts
        #pragma unroll
        for (int it = 0; it < 4; it++) {
            int lin = it * 256 + t;
            int r  = lin >> 4;       // 0..63
            int c4 = lin & 15;       // float4 column group
            float4 v = *(const float4*)&in[eoff + (size_t)(r0 + r) * C + c0 + c4 * 4];
            tile[r][c4 * 4 + 0] = (_Float16)v.x;
            tile[r][c4 * 4 + 1] = (_Float16)v.y;
            tile[r][c4 * 4 + 2] = (_Float16)v.z;
            tile[r][c4 * 4 + 3] = (_Float16)v.w;
        }
        __syncthreads();
        #pragma unroll
        for (int it = 0; it < 4; it++) {
            int lin = it * 256 + t;
            int c  = lin >> 4;       // out row (= original column)
            int r4 = lin & 15;       // group of 4 original rows
            f16x4 o;
            #pragma unroll
            for (int j = 0; j < 4; j++) o[j] = tile[r4 * 4 + j][c];
            *(f16x4*)&out[eoff + (size_t)(c0 + c) * R + r0 + r4 * 4] = o;
        }
    } else if (bid < TRANS_BLOCKS + GATE_BLOCKS) {
        // ---- gating: fp64 logits, softmax, top-2, per-expert lists ----
        const int gtid = (bid - TRANS_BLOCKS) * 256 + t;
        const int n    = gtid >> 6;        // one wave per token
        const int lane = t & 63;
        if (n >= N_TOK) return;
        double part[NEXP];
        #pragma unroll
        for (int e = 0; e < NEXP; e++) part[e] = 0.0;
        for (int d = lane; d < DIM; d += 64) {
            float xv = x[n * DIM + d];
            const float* g = &gw[d * NEXP];
            #pragma unroll
            for (int e = 0; e < NEXP; e++) part[e] += (double)xv * (double)g[e];
        }
        #pragma unroll
        for (int e = 0; e < NEXP; e++) {
            double v = part[e];
            #pragma unroll
            for (int off = 32; off > 0; off >>= 1) v += __shfl_xor(v, off);
            part[e] = v + (double)gb[e];
        }
        if (lane == 0) {
            double mx = part[0];
            #pragma unroll
            for (int e = 1; e < NEXP; e++) mx = fmax(mx, part[e]);
            double ex[NEXP]; double s = 0.0;
            #pragma unroll
            for (int e = 0; e < NEXP; e++) { ex[e] = exp(part[e] - mx); s += ex[e]; }
            int i0 = 0;
            #pragma unroll
            for (int e = 1; e < NEXP; e++) if (ex[e] > ex[i0]) i0 = e;   // first-max tie-break
            int i1 = (i0 == 0) ? 1 : 0;
            #pragma unroll
            for (int e = 0; e < NEXP; e++) if (e != i0 && ex[e] > ex[i1]) i1 = e;
            float g0 = (float)(ex[i0] / s), g1 = (float)(ex[i1] / s);
            float dn = g0 + g1 + 1e-9f;
            float w0 = g0 / dn, w1v = g1 / dn;
            int s0 = atomicAdd(&count[i0], 1);
            tok_list[i0 * N_TOK + s0] = n;  wt_list[i0 * N_TOK + s0] = w0;
            int s1 = atomicAdd(&count[i1], 1);
            tok_list[i1 * N_TOK + s1] = n;  wt_list[i1 * N_TOK + s1] = w1v;
        }
    } else {
        // ---- cast x (fp32 -> f16), one float4 per thread ----
        const int i = (bid - TRANS_BLOCKS - GATE_BLOCKS) * 256 + t;
        float4 v = ((const float4*)x)[i];
        f16x4 o;
        o[0] = (_Float16)v.x; o[1] = (_Float16)v.y;
        o[2] = (_Float16)v.z; o[3] = (_Float16)v.w;
        ((f16x4*)xh)[i] = o;
    }
}

// ---------------- GEMM1: h = gelu(x_gathered @ w1[e] + b1[e]) ----------------
// Round-5 verified structure: 128x128 tile, BK=64, 4 waves (2x2), 4x4
// mfma_f32_16x16x32_f16, 2 k-substeps; both-sides K-chunk XOR swizzle
// (linear gload_lds dest + inverse-swizzled global source + swizzled read
// column) -> 0 bank conflicts. NEW (r6/r7-validated): swapped MFMA operands
// (mfma(bf,af)) so each reg quad covers 4 consecutive h columns ->
// vectorized f16x4 stores + float4 bias loads in the epilogue.
// basep is computed inline from count[] (scan kernel removed).
__global__ __launch_bounds__(256) void mm1_kernel(const _Float16* __restrict__ xh,
                                                  const _Float16* __restrict__ w1t,
                                                  const float* __restrict__ bias1,
                                                  const int* __restrict__ tok_list,
                                                  const int* __restrict__ count,
                                                  _Float16* __restrict__ h) {
    const int e    = blockIdx.y;
    const int cnt  = count[e];
    const int row0 = blockIdx.z * 128;
    if (row0 >= cnt) return;
    const int col0 = blockIdx.x * 128;
    const int t    = threadIdx.x;
    const int lane = t & 63;
    const int wv   = t >> 6;
    const int wy   = wv >> 1, wx = wv & 1;
    const int m_lane = lane & 15, quad = lane >> 4;

    __shared__ __align__(16) _Float16 As[128][64];
    __shared__ __align__(16) _Float16 Bs[128][64];

    const int srow    = t >> 3;                       // 0..31 staging row within group
    const int kin     = (t & 7) * 8;                  // LDS dest chunk (linear, lane order)
    const int kin_src = ((t & 7) ^ (srow & 7)) * 8;   // swizzled global source chunk

    const _Float16* pa[4];
    #pragma unroll
    for (int g = 0; g < 4; g++) {
        int i = row0 + g * 32 + srow; if (i > cnt - 1) i = cnt - 1;
        pa[g] = xh + (size_t)tok_list[e * N_TOK + i] * DIM + kin_src;
    }
    const _Float16* pb[4];
    #pragma unroll
    for (int g = 0; g < 4; g++)
        pb[g] = w1t + (size_t)e * FDIM * DIM + (size_t)(col0 + g * 32 + srow) * DIM + kin_src;

    f32x4 acc[4][4];
    #pragma unroll
    for (int i = 0; i < 4; i++)
        #pragma unroll
        for (int j = 0; j < 4; j++)
            acc[i][j] = (f32x4){0.f, 0.f, 0.f, 0.f};

    const int rsw = (m_lane & 7);   // read-side XOR (row&7 == m_lane&7 for fragment rows)

    for (int kk = 0; kk < DIM; kk += 64) {      // 12 steps
        __syncthreads();                         // previous tile's reads done
        #pragma unroll
        for (int g = 0; g < 4; g++) gload_lds16(pa[g] + kk, &As[g * 32 + srow][kin]);
        #pragma unroll
        for (int g = 0; g < 4; g++) gload_lds16(pb[g] + kk, &Bs[g * 32 + srow][kin]);
        __syncthreads();                         // implicit vmcnt(0) drain
        #pragma unroll
        for (int ks = 0; ks < 2; ks++) {
            const int rc = ((ks * 4 + quad) ^ rsw) * 8;   // swizzled read column
            f16x8 af[4], bf[4];
            #pragma unroll
            for (int i = 0; i < 4; i++)
                af[i] = *(const f16x8*)&As[wy * 64 + i * 16 + m_lane][rc];
            #pragma unroll
            for (int j = 0; j < 4; j++)
                bf[j] = *(const f16x8*)&Bs[wx * 64 + j * 16 + m_lane][rc];
            #pragma unroll
            for (int i = 0; i < 4; i++)
                #pragma unroll
                for (int j = 0; j < 4; j++)
                    acc[i][j] = __builtin_amdgcn_mfma_f32_16x16x32_f16(bf[j], af[i], acc[i][j], 0, 0, 0);
        }
    }

    // inline prefix (scan kernel removed)
    int hbase = 0;
    for (int q = 0; q < NEXP; q++) if (q < e) hbase += count[q];

    // epilogue (swapped-operand layout, r6/r7-validated): value(lane, reg r) =
    //   h[token = row0+wy*64+i*16+m_lane][col = col0+wx*64+j*16+quad*4+r]
    #pragma unroll
    for (int i = 0; i < 4; i++) {
        int gr = row0 + wy * 64 + i * 16 + m_lane;      // token row
        if (gr < cnt) {
            _Float16* hrow = h + (size_t)(hbase + gr) * FDIM;
            #pragma unroll
            for (int j = 0; j < 4; j++) {
                int c = col0 + wx * 64 + j * 16 + quad * 4;
                float4 b4 = *(const float4*)&bias1[e * FDIM + c];
                f16x4 o;
                o[0] = (_Float16)gelu_exact(acc[i][j][0] + b4.x);
                o[1] = (_Float16)gelu_exact(acc[i][j][1] + b4.y);
                o[2] = (_Float16)gelu_exact(acc[i][j][2] + b4.z);
                o[3] = (_Float16)gelu_exact(acc[i][j][3] + b4.w);
                *(f16x4*)&hrow[c] = o;
            }
        }
    }
}

// ---------------- GEMM2: out += gate_w * (h @ w2[e] + b2[e]) ----------------
// Round-5 verified structure: 64x128 tile (768 live blocks, 3/CU), BK=64
// (48 K-steps), 4 waves each own 64 rows x 32 cols (acc[4][2]); same XOR
// swizzle; non-swapped epilogue (wave-op atomics cover 16 consecutive cols,
// WRITE stays ~25 MB). basep inline from count[].
__global__ __launch_bounds__(256) void mm2_kernel(const _Float16* __restrict__ h,
                                                  const _Float16* __restrict__ w2t,
                                                  const float* __restrict__ bias2,
                                                  const int* __restrict__ tok_list,
                                                  const float* __restrict__ wt_list,
                                                  const int* __restrict__ count,
                                                  float* __restrict__ out) {
    const int e    = blockIdx.y;
    const int cnt  = count[e];
    const int row0 = blockIdx.z * 64;
    if (row0 >= cnt) return;
    const int col0 = blockIdx.x * 128;
    const int t    = threadIdx.x;
    const int lane = t & 63;
    const int wv   = t >> 6;            // wave -> 32-col group
    const int m_lane = lane & 15, quad = lane >> 4;

    __shared__ __align__(16) _Float16 As[64][64];
    __shared__ __align__(16) _Float16 Bs[128][64];

    const int srow    = t >> 3;            // 0..31
    const int kin     = (t & 7) * 8;
    const int kin_src = ((t & 7) ^ (srow & 7)) * 8;

    int hbase = 0;
    for (int q = 0; q < NEXP; q++) if (q < e) hbase += count[q];

    const _Float16* pa[2];
    #pragma unroll
    for (int g = 0; g < 2; g++) {
        int i = row0 + g * 32 + srow; if (i > cnt - 1) i = cnt - 1;
        pa[g] = h + (size_t)(hbase + i) * FDIM + kin_src;
    }
    const _Float16* pb[4];
    #pragma unroll
    for (int g = 0; g < 4; g++)
        pb[g] = w2t + (size_t)e * DIM * FDIM + (size_t)(col0 + g * 32 + srow) * FDIM + kin_src;

    f32x4 acc[4][2];
    #pragma unroll
    for (int i = 0; i < 4; i++)
        #pragma unroll
        for (int j = 0; j < 2; j++)
            acc[i][j] = (f32x4){0.f, 0.f, 0.f, 0.f};

    const int rsw = (m_lane & 7);

    for (int kk = 0; kk < FDIM; kk += 64) {     // 48 steps
        __syncthreads();
        #pragma unroll
        for (int g = 0; g < 2; g++) gload_lds16(pa[g] + kk, &As[g * 32 + srow][kin]);
        #pragma unroll
        for (int g = 0; g < 4; g++) gload_lds16(pb[g] + kk, &Bs[g * 32 + srow][kin]);
        __syncthreads();
        #pragma unroll
        for (int ks = 0; ks < 2; ks++) {
            const int rc = ((ks * 4 + quad) ^ rsw) * 8;
            f16x8 af[4], bf[2];
            #pragma unroll
            for (int i = 0; i < 4; i++)
                af[i] = *(const f16x8*)&As[i * 16 + m_lane][rc];
            #pragma unroll
            for (int j = 0; j < 2; j++)
                bf[j] = *(const f16x8*)&Bs[wv * 32 + j * 16 + m_lane][rc];
            #pragma unroll
            for (int i = 0; i < 4; i++)
                #pragma unroll
                for (int j = 0; j < 2; j++)
                    acc[i][j] = __builtin_amdgcn_mfma_f32_16x16x32_f16(af[i], bf[j], acc[i][j], 0, 0, 0);
        }
    }

    #pragma unroll
    for (int i = 0; i < 4; i++) {
        #pragma unroll
        for (int r = 0; r < 4; r++) {
            int rl = i * 16 + quad * 4 + r;         // 0..63
            int gr = row0 + rl;
            if (gr < cnt) {
                int tok   = tok_list[e * N_TOK + gr];
                float wgt = wt_list[e * N_TOK + gr];
                float* orow = out + (size_t)tok * DIM;
                #pragma unroll
                for (int j = 0; j < 2; j++) {
                    int c = col0 + wv * 32 + j * 16 + m_lane;
                    float v = acc[i][j][r] + bias2[e * DIM + c];
                    atomicAdd(&orow[c], wgt * v);
                }
            }
        }
    }
}

extern "C" void kernel_launch(void* const* d_in, const int* in_sizes, int n_in,
                              void* d_out, int out_size, void* d_ws, size_t ws_size,
                              hipStream_t stream) {
    const float* x  = (const float*)d_in[0];
    const float* gw = (const float*)d_in[1];
    const float* gb = (const float*)d_in[2];
    const float* w1 = (const float*)d_in[3];
    const float* b1 = (const float*)d_in[4];
    const float* w2 = (const float*)d_in[5];
    const float* b2 = (const float*)d_in[6];
    float* out = (float*)d_out;

    // workspace layout (all 16B-aligned); total ~132.4 MB
    char* ws = (char*)d_ws;
    _Float16* xh   = (_Float16*)ws;                                    // 4096*768
    _Float16* w1t  = xh  + (size_t)N_TOK * DIM;                        // [E][F][D]
    _Float16* w2t  = w1t + (size_t)NEXP * FDIM * DIM;                  // [E][D][F]
    _Float16* hbuf = w2t + (size_t)NEXP * DIM * FDIM;                  // [2N][F] compact slots
    int*   tok_list = (int*)(hbuf + (size_t)2 * N_TOK * FDIM);         // [E][N]
    float* wt_list  = (float*)(tok_list + NEXP * N_TOK);               // [E][N]
    int*   count    = (int*)(wt_list + NEXP * N_TOK);                  // [E]

    hipMemsetAsync(count, 0, 64, stream);
    hipMemsetAsync(out, 0, (size_t)out_size * sizeof(float), stream);

    // fused pre-pass: transpose+cast w1/w2, gating, cast x  (one launch)
    pre_kernel<<<dim3(PRE_BLOCKS), 256, 0, stream>>>(
        x, gw, gb, w1, w2, xh, w1t, w2t, tok_list, wt_list, count);

    // grid: (cols, experts, rowblocks) -> live blocks are a dense prefix
    mm1_kernel<<<dim3(FDIM / 128, NEXP, N_TOK / 128), 256, 0, stream>>>(
        xh, w1t, b1, tok_list, count, hbuf);
    mm2_kernel<<<dim3(DIM / 128, NEXP, N_TOK / 64), 256, 0, stream>>>(
        hbuf, w2t, b2, tok_list, wt_list, count, out);
}